// Round 2
// baseline (3085.390 us; speedup 1.0000x reference)
//
#include <hip/hip_runtime.h>
#include <hip/hip_cooperative_groups.h>
#include <cstdint>
#include <cstddef>

namespace cg = cooperative_groups;

// Problem constants (reference: B=64, L=512, STEPS=20)
#define LDIM 512
#define BATCH 64
#define NSTEPS 20
#define RPB 128   // rows per block (block owns rows [q*128, q*128+128) of one matrix)
#define QPM 4     // blocks per matrix
#define NTHREADS 1024
#define RPW 8     // rows per wave (16 waves * 8 = 128)
#define CPL 8     // cols per lane (64 lanes * 8 = 512)

__device__ __forceinline__ float relu_f(float x) { return fmaxf(x, 0.0f); }
__device__ __forceinline__ float sign_f(float x) {
  return (x > 0.0f) ? 1.0f : ((x < 0.0f) ? -1.0f : 0.0f);
}
__device__ __forceinline__ float wave_sum(float v) {
  v += __shfl_xor(v, 32);
  v += __shfl_xor(v, 16);
  v += __shfl_xor(v, 8);
  v += __shfl_xor(v, 4);
  v += __shfl_xor(v, 2);
  v += __shfl_xor(v, 1);
  return v;
}
// bf16 pack (RNE) / unpack
__device__ __forceinline__ unsigned short f2bf(float f) {
  unsigned int u = __float_as_uint(f);
  return (unsigned short)((u + 0x7fffu + ((u >> 16) & 1u)) >> 16);
}
__device__ __forceinline__ float bflo(unsigned int d) { return __uint_as_float(d << 16); }
__device__ __forceinline__ float bfhi(unsigned int d) { return __uint_as_float(d & 0xffff0000u); }

__device__ __forceinline__ void ld8(const float* __restrict__ p, float* d) {
  const float4 v0 = *(const float4*)p;
  const float4 v1 = *(const float4*)(p + 4);
  d[0] = v0.x; d[1] = v0.y; d[2] = v0.z; d[3] = v0.w;
  d[4] = v1.x; d[5] = v1.y; d[6] = v1.z; d[7] = v1.w;
}
__device__ __forceinline__ void st8(float* __restrict__ p, const float* s) {
  float4 v0, v1;
  v0.x = s[0]; v0.y = s[1]; v0.z = s[2]; v0.w = s[3];
  v1.x = s[4]; v1.y = s[5]; v1.z = s[6]; v1.w = s[7];
  *(float4*)p = v0;
  *(float4*)(p + 4) = v1;
}

// Persistent cooperative kernel: whole pipeline in ONE launch.
//  - Ah state: 64 fp32 registers per thread (8 rows x 8 cols)
//  - MU = masked symmetrized scores: bf16 in LDS (128 KiB), sentinel -1e30 for M==0
//  - cross-step coupling: row/col partial sums of M.*Ah via global + grid.sync
//  - Lm[512] maintained redundantly (identically) per block in LDS
__global__ __launch_bounds__(NTHREADS) void fused_all(
    const float* __restrict__ scores, const float* __restrict__ Mmask,
    const float* __restrict__ rho_p, const float* __restrict__ s_ptr,
    const float* __restrict__ w_ptr, const float* __restrict__ alpha_ptr,
    const float* __restrict__ belt_ptr, const float* __restrict__ lra_ptr,
    const float* __restrict__ lrb_ptr, float* __restrict__ out,
    float* __restrict__ stage, float* __restrict__ rowsum0,
    float* __restrict__ rowsum1, float* __restrict__ colpart0,
    float* __restrict__ colpart1) {
  __shared__ unsigned short MUs[RPB][LDIM];  // 128 KiB
  __shared__ float LmS[LDIM];                // 2 KiB  (per-matrix Lm, replicated)
  __shared__ float lmsgS[LDIM];              // 2 KiB
  __shared__ float colredS[8][LDIM];         // 16 KiB
  __shared__ float rowredS[RPB];             // 0.5 KiB

  cg::grid_group grid = cg::this_grid();

  const int tid = threadIdx.x;
  const int lane = tid & 63;
  const int wid = tid >> 6;
  const int mat = blockIdx.x >> 2;
  const int q = blockIdx.x & 3;
  const int r0 = q * RPB;
  const int j0 = lane * CPL;

  const float sval = s_ptr[0];
  const float wv = w_ptr[0];
  const float lra = lra_ptr[0];
  const float lrb = lrb_ptr[0];
  float at = alpha_ptr[0];   // alpha * lra^t, updated per step
  float bm = belt_ptr[0];    // belt * lrb^(t-1) for t>=1, updated per step

  const size_t matbase = (size_t)mat * LDIM * LDIM;

  float a[RPW][CPL];     // Ah state, register-resident for the whole kernel
  float colacc[CPL];
  float rowacc[RPW];

  // ---------------- init: load scores, build MU, partials of A0 ----------------
#pragma unroll
  for (int r = 0; r < RPW; r++) {
    const int i = r0 + wid * RPW + r;
    ld8(scores + matbase + (size_t)i * LDIM + j0, a[r]);
    rowacc[r] = 0.0f;
  }
#pragma unroll
  for (int c = 0; c < CPL; c++) {
    const int j = j0 + c;
    // column slice via transposed rows; M is symmetric so M[j][i] == M[i][j]
    const size_t jrow = matbase + (size_t)j * LDIM + r0 + wid * RPW;
    float tT[RPW], mT[RPW];
    ld8(scores + jrow, tT);
    ld8(Mmask + jrow, mT);
    float cacc = 0.0f;
#pragma unroll
    for (int r = 0; r < RPW; r++) {
      const float mu = 0.5f * (a[r][c] + tT[r]) - sval;
      const bool msk = (mT[r] != 0.0f);
      const float contrib = msk ? (mu + sval) : 0.0f;  // = A0 element (symmetric)
      rowacc[r] += contrib;
      cacc += contrib;
      MUs[wid * RPW + r][j] = f2bf(msk ? mu : -1e30f);
    }
    colacc[c] = cacc;
  }
#pragma unroll
  for (int r = 0; r < RPW; r++) {
    const float tot = wave_sum(rowacc[r]);
    if (lane == 0) rowredS[wid * RPW + r] = tot;
  }

  // shared reduce+publish (used by init with parity 0 and by each step)
  auto reduce_publish = [&](float* __restrict__ rowsumW, float* __restrict__ colpartW) {
    __syncthreads();
    if (wid < 8) {
      st8(&colredS[wid][j0], colacc);
    }
    __syncthreads();
    if (wid >= 8) {
      float tmp[CPL];
      ld8(&colredS[wid - 8][j0], tmp);
#pragma unroll
      for (int c = 0; c < CPL; c++) tmp[c] += colacc[c];
      st8(&colredS[wid - 8][j0], tmp);
    }
    __syncthreads();
    if (tid < LDIM) {
      float cs = 0.0f;
#pragma unroll
      for (int k = 0; k < 8; k++) cs += colredS[k][tid];
      colpartW[((size_t)mat * QPM + q) * LDIM + tid] = cs;
    } else if (tid < LDIM + RPB) {
      rowsumW[(size_t)mat * LDIM + r0 + (tid - LDIM)] = rowredS[tid - LDIM];
    }
    __threadfence();
  };

  reduce_publish(rowsum0, colpart0);
  grid.sync();

  // ---------------- 20 fused steps ----------------
#pragma unroll 1
  for (int t = 0; t < NSTEPS; t++) {
    const float* rowsumR = (t & 1) ? rowsum1 : rowsum0;
    const float* colpartR = (t & 1) ? colpart1 : colpart0;
    float* rowsumW = (t & 1) ? rowsum0 : rowsum1;
    float* colpartW = (t & 1) ? colpart0 : colpart1;

    // prologue: Lm update + lmsg for all 512 rows of this matrix (redundant/block)
    if (tid < LDIM) {
      const float srow = rowsumR[(size_t)mat * LDIM + tid];
      float scol = 0.0f;
#pragma unroll
      for (int q2 = 0; q2 < QPM; q2++)
        scol += colpartR[((size_t)mat * QPM + q2) * LDIM + tid];
      const float rd = 0.5f * (srow + scol) - 1.0f;
      const float lm = (t == 0) ? (wv * relu_f(rd)) : (LmS[tid] + bm * relu_f(rd));
      LmS[tid] = lm;
      lmsgS[tid] = lm * sign_f(rd);
    }
    __syncthreads();

    float lmj[CPL];
    ld8(&lmsgS[j0], lmj);
#pragma unroll
    for (int c = 0; c < CPL; c++) colacc[c] = 0.0f;

#pragma unroll
    for (int r = 0; r < RPW; r++) {
      const int il = wid * RPW + r;
      const int i = r0 + il;
      const float lmi = lmsgS[i];
      const uint4 mu4 = *(const uint4*)&MUs[il][j0];
      float rho[CPL];
      ld8(rho_p + (size_t)i * LDIM + j0, rho);
      float muf[CPL];
      muf[0] = bflo(mu4.x); muf[1] = bfhi(mu4.x);
      muf[2] = bflo(mu4.y); muf[3] = bfhi(mu4.y);
      muf[4] = bflo(mu4.z); muf[5] = bfhi(mu4.z);
      muf[6] = bflo(mu4.w); muf[7] = bfhi(mu4.w);
      float rowc = 0.0f;
#pragma unroll
      for (int c = 0; c < CPL; c++) {
        const bool msk = (muf[c] > -1e29f);
        const float g = msk ? (muf[c] - lmi - lmj[c]) : 0.0f;
        const float u = a[r][c] * fmaf(at, g, 1.0f);
        const float v = fminf(relu_f(fabsf(u) - rho[c] * at), 1.0f);
        a[r][c] = v;
        const float cm = msk ? v : 0.0f;
        rowc += cm;
        colacc[c] += cm;
      }
      const float tot = wave_sum(rowc);
      if (lane == 0) rowredS[il] = tot;
    }

    reduce_publish(rowsumW, colpartW);
    grid.sync();

    at *= lra;
    if (t >= 1) bm *= lrb;
  }

  // ---------------- final: A = 0.5*(Ah + Ah^T) .* M ----------------
#pragma unroll
  for (int r = 0; r < RPW; r++) {
    const int i = r0 + wid * RPW + r;
    st8(stage + matbase + (size_t)i * LDIM + j0, a[r]);
  }
  __threadfence();
  grid.sync();

#pragma unroll
  for (int c = 0; c < CPL; c++) {
    const int j = j0 + c;
    const size_t jrow = matbase + (size_t)j * LDIM + r0 + wid * RPW;
    float tT[RPW];
    ld8(stage + jrow, tT);
#pragma unroll
    for (int r = 0; r < RPW; r++) a[r][c] = 0.5f * (a[r][c] + tT[r]);
  }
#pragma unroll
  for (int r = 0; r < RPW; r++) {
    const int i = r0 + wid * RPW + r;
    float m8[CPL];
    ld8(Mmask + matbase + (size_t)i * LDIM + j0, m8);
    float o8[CPL];
#pragma unroll
    for (int c = 0; c < CPL; c++) o8[c] = a[r][c] * m8[c];
    st8(out + matbase + (size_t)i * LDIM + j0, o8);
  }
}

// ---------------------------------------------------------------------------
extern "C" void kernel_launch(void* const* d_in, const int* in_sizes, int n_in,
                              void* d_out, int out_size, void* d_ws,
                              size_t ws_size, hipStream_t stream) {
  const float* scores = (const float*)d_in[0];
  const float* M = (const float*)d_in[1];
  const float* s_p = (const float*)d_in[2];
  const float* w_p = (const float*)d_in[3];
  const float* rho = (const float*)d_in[4];
  const float* alpha_p = (const float*)d_in[5];
  const float* belt_p = (const float*)d_in[6];
  const float* lra_p = (const float*)d_in[7];
  const float* lrb_p = (const float*)d_in[8];
  float* out = (float*)d_out;

  // workspace: stage (64 MB) + row/col partial double-buffers (~1.3 MB)
  char* ws = (char*)d_ws;
  size_t off = 0;
  auto walloc = [&](size_t bytes) -> float* {
    float* p = (float*)(ws + off);
    off += (bytes + 255) & ~(size_t)255;
    return p;
  };
  float* stage = walloc((size_t)BATCH * LDIM * LDIM * 4);
  float* rowsum0 = walloc((size_t)BATCH * LDIM * 4);
  float* rowsum1 = walloc((size_t)BATCH * LDIM * 4);
  float* colpart0 = walloc((size_t)BATCH * QPM * LDIM * 4);
  float* colpart1 = walloc((size_t)BATCH * QPM * LDIM * 4);

  void* args[] = {
      (void*)&scores, (void*)&M,      (void*)&rho,      (void*)&s_p,
      (void*)&w_p,    (void*)&alpha_p, (void*)&belt_p,  (void*)&lra_p,
      (void*)&lrb_p,  (void*)&out,    (void*)&stage,    (void*)&rowsum0,
      (void*)&rowsum1, (void*)&colpart0, (void*)&colpart1};

  hipLaunchCooperativeKernel((void*)fused_all, dim3(BATCH * QPM), dim3(NTHREADS),
                             args, 0, stream);
}

// Round 4
// 2280.826 us; speedup vs baseline: 1.3528x; 1.3528x over previous
//
#include <hip/hip_runtime.h>
#include <hip/hip_cooperative_groups.h>
#include <cstdint>
#include <cstddef>

namespace cg = cooperative_groups;

// Problem constants (reference: B=64, L=512, STEPS=20)
#define LDIM 512
#define BATCH 64
#define NSTEPS 20
#define RPB 128   // rows per block (block owns rows [q*128, q*128+128) of one matrix)
#define QPM 4     // blocks per matrix
#define NTHREADS 1024
#define RPW 8     // rows per wave (16 waves * 8 = 128)
#define CPL 8     // cols per lane (64 lanes * 8 = 512)

__device__ __forceinline__ float relu_f(float x) { return fmaxf(x, 0.0f); }
__device__ __forceinline__ float sign_f(float x) {
  return (x > 0.0f) ? 1.0f : ((x < 0.0f) ? -1.0f : 0.0f);
}
__device__ __forceinline__ float wave_sum(float v) {
  v += __shfl_xor(v, 32);
  v += __shfl_xor(v, 16);
  v += __shfl_xor(v, 8);
  v += __shfl_xor(v, 4);
  v += __shfl_xor(v, 2);
  v += __shfl_xor(v, 1);
  return v;
}
// bf16 pack (RNE) / unpack
__device__ __forceinline__ unsigned short f2bf(float f) {
  unsigned int u = __float_as_uint(f);
  return (unsigned short)((u + 0x7fffu + ((u >> 16) & 1u)) >> 16);
}
__device__ __forceinline__ float bflo(unsigned int d) { return __uint_as_float(d << 16); }
__device__ __forceinline__ float bfhi(unsigned int d) { return __uint_as_float(d & 0xffff0000u); }

__device__ __forceinline__ void ld8(const float* __restrict__ p, float* d) {
  const float4 v0 = *(const float4*)p;
  const float4 v1 = *(const float4*)(p + 4);
  d[0] = v0.x; d[1] = v0.y; d[2] = v0.z; d[3] = v0.w;
  d[4] = v1.x; d[5] = v1.y; d[6] = v1.z; d[7] = v1.w;
}
__device__ __forceinline__ void st8(float* __restrict__ p, const float* s) {
  float4 v0, v1;
  v0.x = s[0]; v0.y = s[1]; v0.z = s[2]; v0.w = s[3];
  v1.x = s[4]; v1.y = s[5]; v1.z = s[6]; v1.w = s[7];
  *(float4*)p = v0;
  *(float4*)(p + 4) = v1;
}

// 4-block (per-matrix) barrier. Counter is monotonic (zeroed once at kernel
// start, published by the single initial grid.sync). Cooperative launch
// guarantees all 256 blocks are co-resident, so spinning is deadlock-free.
__device__ __forceinline__ void mat_barrier(unsigned int* ctr, unsigned int target) {
  __syncthreads();  // all waves' stores issued before the signal
  if (threadIdx.x == 0) {
    __hip_atomic_fetch_add(ctr, 1u, __ATOMIC_RELEASE, __HIP_MEMORY_SCOPE_AGENT);
    while (__hip_atomic_load(ctr, __ATOMIC_RELAXED, __HIP_MEMORY_SCOPE_AGENT) < target)
      __builtin_amdgcn_s_sleep(1);
  }
  __syncthreads();
  __threadfence();  // acquire: make peers' stores visible before we read them
}

// Persistent cooperative kernel: whole pipeline in ONE launch.
//  - Ah state: 64 fp32 registers per thread (8 rows x 8 cols)
//  - MU = masked symmetrized scores: bf16 in LDS (128 KiB), sentinel -1e30 for M==0
//  - cross-step coupling: row/col partial sums of M.*Ah via global + 4-block barrier
//  - __launch_bounds__(1024, 4): 128-VGPR budget (LDS already caps at 1 block/CU,
//    so 4 waves/EU is the true occupancy; the R2 default budget of 64 spilled
//    the whole state array to scratch -> 2.2 GB HBM traffic, 3 ms)
__global__ __launch_bounds__(NTHREADS, 4) void fused_all(
    const float* __restrict__ scores, const float* __restrict__ Mmask,
    const float* __restrict__ rho_p, const float* __restrict__ s_ptr,
    const float* __restrict__ w_ptr, const float* __restrict__ alpha_ptr,
    const float* __restrict__ belt_ptr, const float* __restrict__ lra_ptr,
    const float* __restrict__ lrb_ptr, float* __restrict__ out,
    float* __restrict__ stage, float* __restrict__ rowsum0,
    float* __restrict__ rowsum1, float* __restrict__ colpart0,
    float* __restrict__ colpart1, unsigned int* __restrict__ ctrs) {
  __shared__ unsigned short MUs[RPB][LDIM];  // 128 KiB
  __shared__ float LmS[LDIM];                // 2 KiB  (per-matrix Lm, replicated)
  __shared__ float lmsgS[LDIM];              // 2 KiB
  __shared__ float colredS[8][LDIM];         // 16 KiB
  __shared__ float rowredS[RPB];             // 0.5 KiB

  cg::grid_group grid = cg::this_grid();

  const int tid = threadIdx.x;
  const int lane = tid & 63;
  const int wid = tid >> 6;
  const int mat = blockIdx.x >> 2;
  const int q = blockIdx.x & 3;
  const int r0 = q * RPB;
  const int j0 = lane * CPL;

  unsigned int* myctr = ctrs + (size_t)mat * 32;  // 128 B apart per matrix
  if (q == 0 && tid == 0) *myctr = 0u;  // published by the initial grid.sync

  const float sval = s_ptr[0];
  const float wv = w_ptr[0];
  const float lra = lra_ptr[0];
  const float lrb = lrb_ptr[0];
  float at = alpha_ptr[0];   // alpha * lra^t, updated per step
  float bm = belt_ptr[0];    // belt * lrb^(t-1) for t>=1, updated per step

  const size_t matbase = (size_t)mat * LDIM * LDIM;

  float a[RPW][CPL];     // Ah state, register-resident for the whole kernel
  float colacc[CPL];
  float rowacc[RPW];

  // ---------------- init: load scores, build MU, partials of A0 ----------------
#pragma unroll 2
  for (int r = 0; r < RPW; r++) {
    const int i = r0 + wid * RPW + r;
    ld8(scores + matbase + (size_t)i * LDIM + j0, a[r]);
    rowacc[r] = 0.0f;
  }
#pragma unroll 2
  for (int c = 0; c < CPL; c++) {
    const int j = j0 + c;
    // column slice via transposed rows; M is symmetric so M[j][i] == M[i][j]
    const size_t jrow = matbase + (size_t)j * LDIM + r0 + wid * RPW;
    float tT[RPW], mT[RPW];
    ld8(scores + jrow, tT);
    ld8(Mmask + jrow, mT);
    float cacc = 0.0f;
#pragma unroll
    for (int r = 0; r < RPW; r++) {
      const float mu = 0.5f * (a[r][c] + tT[r]) - sval;
      const bool msk = (mT[r] != 0.0f);
      const float contrib = msk ? (mu + sval) : 0.0f;  // = A0 element (symmetric)
      rowacc[r] += contrib;
      cacc += contrib;
      MUs[wid * RPW + r][j] = f2bf(msk ? mu : -1e30f);
    }
    colacc[c] = cacc;
  }
#pragma unroll
  for (int r = 0; r < RPW; r++) {
    const float tot = wave_sum(rowacc[r]);
    if (lane == 0) rowredS[wid * RPW + r] = tot;
  }

  // shared reduce+publish (used by init and by each step)
  auto reduce_publish = [&](float* __restrict__ rowsumW, float* __restrict__ colpartW) {
    __syncthreads();
    if (wid < 8) {
      st8(&colredS[wid][j0], colacc);
    }
    __syncthreads();
    if (wid >= 8) {
      float tmp[CPL];
      ld8(&colredS[wid - 8][j0], tmp);
#pragma unroll
      for (int c = 0; c < CPL; c++) tmp[c] += colacc[c];
      st8(&colredS[wid - 8][j0], tmp);
    }
    __syncthreads();
    if (tid < LDIM) {
      float cs = 0.0f;
#pragma unroll
      for (int k = 0; k < 8; k++) cs += colredS[k][tid];
      colpartW[((size_t)mat * QPM + q) * LDIM + tid] = cs;
    } else if (tid < LDIM + RPB) {
      rowsumW[(size_t)mat * LDIM + r0 + (tid - LDIM)] = rowredS[tid - LDIM];
    }
  };

  reduce_publish(rowsum0, colpart0);
  grid.sync();  // covers: init partials + zeroed barrier counters

  // ---------------- 20 fused steps ----------------
#pragma unroll 1
  for (int t = 0; t < NSTEPS; t++) {
    const float* rowsumR = (t & 1) ? rowsum1 : rowsum0;
    const float* colpartR = (t & 1) ? colpart1 : colpart0;
    float* rowsumW = (t & 1) ? rowsum0 : rowsum1;
    float* colpartW = (t & 1) ? colpart0 : colpart1;

    // prologue: Lm update + lmsg for all 512 rows of this matrix (redundant/block)
    if (tid < LDIM) {
      const float srow = rowsumR[(size_t)mat * LDIM + tid];
      float scol = 0.0f;
#pragma unroll
      for (int q2 = 0; q2 < QPM; q2++)
        scol += colpartR[((size_t)mat * QPM + q2) * LDIM + tid];
      const float rd = 0.5f * (srow + scol) - 1.0f;
      const float lm = (t == 0) ? (wv * relu_f(rd)) : (LmS[tid] + bm * relu_f(rd));
      LmS[tid] = lm;
      lmsgS[tid] = lm * sign_f(rd);
    }
    __syncthreads();

    float lmj[CPL];
    ld8(&lmsgS[j0], lmj);
#pragma unroll
    for (int c = 0; c < CPL; c++) colacc[c] = 0.0f;

#pragma unroll 2
    for (int r = 0; r < RPW; r++) {
      const int il = wid * RPW + r;
      const int i = r0 + il;
      const float lmi = lmsgS[i];
      const float* rrow = rho_p + (size_t)i * LDIM + j0;
      float rowc = 0.0f;
#pragma unroll
      for (int h = 0; h < 2; h++) {  // 4-column chunks to bound live temps
        const uint2 mu2 = *(const uint2*)&MUs[il][j0 + 4 * h];
        const float4 rho4 = *(const float4*)(rrow + 4 * h);
        float muf[4], rh[4];
        muf[0] = bflo(mu2.x); muf[1] = bfhi(mu2.x);
        muf[2] = bflo(mu2.y); muf[3] = bfhi(mu2.y);
        rh[0] = rho4.x; rh[1] = rho4.y; rh[2] = rho4.z; rh[3] = rho4.w;
#pragma unroll
        for (int c4 = 0; c4 < 4; c4++) {
          const int c = 4 * h + c4;
          const bool msk = (muf[c4] > -1e29f);
          const float g = msk ? (muf[c4] - lmi - lmj[c]) : 0.0f;
          const float u = a[r][c] * fmaf(at, g, 1.0f);
          const float v = fminf(relu_f(fabsf(u) - rh[c4] * at), 1.0f);
          a[r][c] = v;
          const float cm = msk ? v : 0.0f;
          rowc += cm;
          colacc[c] += cm;
        }
      }
      const float tot = wave_sum(rowc);
      if (lane == 0) rowredS[il] = tot;
    }

    reduce_publish(rowsumW, colpartW);
    mat_barrier(myctr, 4u * (unsigned)(t + 1));

    at *= lra;
    if (t >= 1) bm *= lrb;
  }

  // ---------------- final: A = 0.5*(Ah + Ah^T) .* M ----------------
#pragma unroll 2
  for (int r = 0; r < RPW; r++) {
    const int i = r0 + wid * RPW + r;
    st8(stage + matbase + (size_t)i * LDIM + j0, a[r]);
  }
  mat_barrier(myctr, 4u * (unsigned)(NSTEPS + 1));

#pragma unroll 2
  for (int c = 0; c < CPL; c++) {
    const int j = j0 + c;
    const size_t jrow = matbase + (size_t)j * LDIM + r0 + wid * RPW;
    float tT[RPW];
    ld8(stage + jrow, tT);
#pragma unroll
    for (int r = 0; r < RPW; r++) a[r][c] = 0.5f * (a[r][c] + tT[r]);
  }
#pragma unroll 2
  for (int r = 0; r < RPW; r++) {
    const int i = r0 + wid * RPW + r;
    float m8[CPL];
    ld8(Mmask + matbase + (size_t)i * LDIM + j0, m8);
    float o8[CPL];
#pragma unroll
    for (int c = 0; c < CPL; c++) o8[c] = a[r][c] * m8[c];
    st8(out + matbase + (size_t)i * LDIM + j0, o8);
  }
}

// ---------------------------------------------------------------------------
extern "C" void kernel_launch(void* const* d_in, const int* in_sizes, int n_in,
                              void* d_out, int out_size, void* d_ws,
                              size_t ws_size, hipStream_t stream) {
  const float* scores = (const float*)d_in[0];
  const float* M = (const float*)d_in[1];
  const float* s_p = (const float*)d_in[2];
  const float* w_p = (const float*)d_in[3];
  const float* rho = (const float*)d_in[4];
  const float* alpha_p = (const float*)d_in[5];
  const float* belt_p = (const float*)d_in[6];
  const float* lra_p = (const float*)d_in[7];
  const float* lrb_p = (const float*)d_in[8];
  float* out = (float*)d_out;

  // workspace: stage (64 MB) + partial double-buffers (~1.3 MB) + barrier ctrs
  char* ws = (char*)d_ws;
  size_t off = 0;
  auto walloc = [&](size_t bytes) -> void* {
    void* p = (void*)(ws + off);
    off += (bytes + 255) & ~(size_t)255;
    return p;
  };
  float* stage = (float*)walloc((size_t)BATCH * LDIM * LDIM * 4);
  float* rowsum0 = (float*)walloc((size_t)BATCH * LDIM * 4);
  float* rowsum1 = (float*)walloc((size_t)BATCH * LDIM * 4);
  float* colpart0 = (float*)walloc((size_t)BATCH * QPM * LDIM * 4);
  float* colpart1 = (float*)walloc((size_t)BATCH * QPM * LDIM * 4);
  unsigned int* ctrs = (unsigned int*)walloc((size_t)BATCH * 32 * 4);

  void* args[] = {
      (void*)&scores,  (void*)&M,        (void*)&rho,     (void*)&s_p,
      (void*)&w_p,     (void*)&alpha_p,  (void*)&belt_p,  (void*)&lra_p,
      (void*)&lrb_p,   (void*)&out,      (void*)&stage,   (void*)&rowsum0,
      (void*)&rowsum1, (void*)&colpart0, (void*)&colpart1, (void*)&ctrs};

  (void)hipLaunchCooperativeKernel((void*)fused_all, dim3(BATCH * QPM),
                                   dim3(NTHREADS), args, 0, stream);
}